// Round 10
// baseline (152.076 us; speedup 1.0000x reference)
//
#include <hip/hip_runtime.h>
#include <hip/hip_bf16.h>
#include <math.h>

// Problem: B=4, L=2048 (M = 8192 rows), D_MODEL = 768, N_STATE = 16.
// y[row,d] = x[row,d] * softplus((x@W1+b1)[row,d]) * dot(x@W2+b2, x@W3+b3)[row]
// (dA*h0 term is identically zero; A unused.)
// Ledger (R9): 116.4 total = ~62 harness fills (fixed) + gemm ~30 + prep ~13
// + sgemm ~6 + gaps. R10: barrier-free direct-from-global gemm (no LDS) --
// fragments are line-coalesced from global; 2-stage register pipeline.

#define M_ROWS 8192
#define DM 768
#define NS 16

typedef short bf16x8 __attribute__((ext_vector_type(8)));
typedef float f32x4 __attribute__((ext_vector_type(4)));

__device__ __forceinline__ unsigned short f2bf(float f) {
    union { float f; unsigned u; } v; v.f = f;
    unsigned r = v.u + 0x7FFF + ((v.u >> 16) & 1);   // RNE
    return (unsigned short)(r >> 16);
}
__device__ __forceinline__ float bf2f(unsigned short h) {
    union { unsigned u; float f; } v; v.u = ((unsigned)h) << 16; return v.f;
}
__device__ __forceinline__ void async16(const void* g, void* l) {
    __builtin_amdgcn_global_load_lds(
        (const __attribute__((address_space(1))) void*)g,
        (__attribute__((address_space(3))) void*)l,
        16, 0, 0);
}
// branchless stable softplus: max(v,0) + log(1+exp(-|v|)); HW exp/log.
__device__ __forceinline__ float softplus_fast(float v) {
    return fmaxf(v, 0.f) + __logf(1.f + __expf(-fabsf(v)));
}

// ---- kernel 1: prep (pure streaming, block-specialized; R9-exact) -------
__global__ __launch_bounds__(256) void prep_kernel(
    const float* __restrict__ x,
    const float* __restrict__ W1,
    const float* __restrict__ W2,
    const float* __restrict__ W3,
    unsigned short* __restrict__ xb,
    unsigned short* __restrict__ w1t,
    unsigned short* __restrict__ w23t)
{
    __shared__ float tile[32][33];
    const int bid = blockIdx.x;
    const int tid = threadIdx.x;
    if (bid < 32) {
        const int n = bid, i = n >> 1;
        const float* src = (n & 1) ? W3 : W2;
        #pragma unroll
        for (int e = 0; e < 3; ++e) {
            int k = e * 256 + tid;
            w23t[n * DM + k] = f2bf(src[k * NS + i]);
        }
    } else if (bid < 608) {
        const int b2i = bid - 32;                // 0..575
        const int n0 = (b2i % 24) * 32, k0 = (b2i / 24) * 32;
        const int tx = tid & 31, ty = tid >> 5;  // 32 x 8
        #pragma unroll
        for (int i = 0; i < 4; ++i) {
            int k = ty + i * 8;
            tile[k][tx] = W1[(k0 + k) * DM + n0 + tx];
        }
        __syncthreads();
        #pragma unroll
        for (int i = 0; i < 4; ++i) {
            int n = ty + i * 8;
            w1t[(n0 + n) * DM + k0 + tx] = f2bf(tile[tx][n]);
        }
    } else {
        int i = (bid - 608) * 256 + tid;         // one float4 per thread
        float4 v = ((const float4*)x)[i];
        ushort4 o;
        o.x = f2bf(v.x); o.y = f2bf(v.y); o.z = f2bf(v.z); o.w = f2bf(v.w);
        ((ushort4*)xb)[i] = o;
    }
}

// ---- kernel 2: s via MFMA (verified; R9-exact) --------------------------
__global__ __launch_bounds__(256) void sgemm_kernel(
    const unsigned short* __restrict__ xb,
    const unsigned short* __restrict__ w23t,
    const float* __restrict__ b2, const float* __restrict__ b3,
    float* __restrict__ s_out)
{
    __shared__ unsigned short Al[64 * 64];
    __shared__ unsigned short Bl[32 * 64];
    const int m0 = blockIdx.x * 64;
    const int tid = threadIdx.x, lane = tid & 63, wave = tid >> 6;
    const int l15 = lane & 15, quad = lane >> 4;

    f32x4 acc[2];
    acc[0] = (f32x4){0.f,0.f,0.f,0.f};
    acc[1] = (f32x4){0.f,0.f,0.f,0.f};

    for (int k0 = 0; k0 < DM; k0 += 64) {
        #pragma unroll
        for (int i = 0; i < 2; ++i) {
            int ch = tid + i * 256;
            int r = ch >> 3, jg = (ch & 7) ^ (r & 7);
            async16(xb + (m0 + r) * DM + k0 + jg * 8, Al + ch * 8);
        }
        {
            int ch = tid;
            int r = ch >> 3, jg = (ch & 7) ^ (r & 7);
            async16(w23t + r * DM + k0 + jg * 8, Bl + ch * 8);
        }
        __syncthreads();
        #pragma unroll
        for (int kk = 0; kk < 2; ++kk) {
            int rr = wave * 16 + l15;
            int ja = (kk * 4 + quad) ^ (rr & 7);
            bf16x8 af = *(const bf16x8*)(Al + rr * 64 + ja * 8);
            #pragma unroll
            for (int t = 0; t < 2; ++t) {
                int rb = t * 16 + l15;
                int jb = (kk * 4 + quad) ^ (rb & 7);
                bf16x8 bfr = *(const bf16x8*)(Bl + rb * 64 + jb * 8);
                acc[t] = __builtin_amdgcn_mfma_f32_16x16x32_bf16(
                    af, bfr, acc[t], 0, 0, 0);
            }
        }
        __syncthreads();
    }

    float sacc[4] = {0.f, 0.f, 0.f, 0.f};
    #pragma unroll
    for (int t = 0; t < 2; ++t) {
        int p = t * 8 + (l15 >> 1);
        float bB = b2[p], bC = b3[p];
        #pragma unroll
        for (int r = 0; r < 4; ++r) {
            float v = acc[t][r];
            float pv = __shfl_xor(v, 1, 64);
            float term = (l15 & 1) ? (pv + bB) * (v + bC)
                                   : (v + bB) * (pv + bC);
            sacc[r] += term;
        }
    }
    #pragma unroll
    for (int r = 0; r < 4; ++r) {
        sacc[r] += __shfl_xor(sacc[r], 1, 64);
        sacc[r] += __shfl_xor(sacc[r], 2, 64);
        sacc[r] += __shfl_xor(sacc[r], 4, 64);
        sacc[r] += __shfl_xor(sacc[r], 8, 64);
    }
    if (l15 == 0) {
        #pragma unroll
        for (int r = 0; r < 4; ++r)
            s_out[m0 + wave * 16 + quad * 4 + r] = 0.5f * sacc[r];
    }
}

// ---- kernel 3: fused GEMM, barrier-free direct-from-global --------------
// No LDS. Each wave loads its MFMA fragments straight from global: the
// 16x16x32 A-frag pattern (rows m0+..+l15, k=quad*8) makes one wave load
// touch 16 complete 64B lines -- fully coalesced; same for B from n-major
// w1t. Both operands are L2-resident (xb 12.6 MB, w1t 1.2 MB). 2-stage
// register pipeline hides L2 latency; no __syncthreads anywhere, so all
// waves progress independently (the R9 lesson: barrier lockstep was the
// structural limit). 128x64 block tile, wave = 64x32. 768 blocks, XCD swz.
__global__ __launch_bounds__(256) void gemm_fused_kernel(
    const unsigned short* __restrict__ xb,    // [8192][768] bf16
    const unsigned short* __restrict__ w1t,   // [768][768] bf16, n-major
    const float* __restrict__ b1,
    const float* __restrict__ s_arr,
    float* __restrict__ y)
{
    const int b = blockIdx.x;
    const int c = b & 7, j = b >> 3;          // j in [0,96)
    const int m0 = (c * 8 + j / 12) * 128;
    const int n0 = (j % 12) * 64;
    const int lane = threadIdx.x & 63;
    const int wave = threadIdx.x >> 6;
    const int wm = wave >> 1, wn = wave & 1;
    const int l15 = lane & 15, quad = lane >> 4;

    // wave-fragment base pointers (k-offset added per step)
    const unsigned short* Abase = xb  + (size_t)(m0 + wm * 64 + l15) * DM + quad * 8;
    const unsigned short* Bbase = w1t + (size_t)(n0 + wn * 32 + l15) * DM + quad * 8;

    f32x4 acc[4][2];
    #pragma unroll
    for (int i = 0; i < 4; ++i)
        #pragma unroll
        for (int jj = 0; jj < 2; ++jj)
            acc[i][jj] = (f32x4){0.f, 0.f, 0.f, 0.f};

#define LOAD_FRAGS(da, db, koff)                                              \
    {                                                                         \
        _Pragma("unroll") for (int i = 0; i < 4; ++i)                         \
            _Pragma("unroll") for (int kk = 0; kk < 2; ++kk)                  \
                da[i][kk] = *(const bf16x8*)(Abase + (size_t)i * 16 * DM      \
                                             + (koff) + kk * 32);             \
        _Pragma("unroll") for (int jj = 0; jj < 2; ++jj)                      \
            _Pragma("unroll") for (int kk = 0; kk < 2; ++kk)                  \
                db[jj][kk] = *(const bf16x8*)(Bbase + (size_t)jj * 16 * DM    \
                                              + (koff) + kk * 32);            \
    }
#define DO_MFMA(sa, sb)                                                       \
    {                                                                         \
        _Pragma("unroll") for (int kk = 0; kk < 2; ++kk)                      \
            _Pragma("unroll") for (int i = 0; i < 4; ++i)                     \
                _Pragma("unroll") for (int jj = 0; jj < 2; ++jj)              \
                    acc[i][jj] = __builtin_amdgcn_mfma_f32_16x16x32_bf16(     \
                        sa[i][kk], sb[jj][kk], acc[i][jj], 0, 0, 0);          \
    }

    bf16x8 aA[4][2], bA[2][2], aB[4][2], bB[2][2];
    LOAD_FRAGS(aA, bA, 0);
    #pragma unroll
    for (int s2 = 0; s2 < 6; ++s2) {
        LOAD_FRAGS(aB, bB, (2 * s2 + 1) * 64);
        DO_MFMA(aA, bA);
        if (s2 < 5)
            LOAD_FRAGS(aA, bA, (2 * s2 + 2) * 64);
        DO_MFMA(aB, bB);
    }
#undef LOAD_FRAGS
#undef DO_MFMA

    // epilogue: C/D layout col = lane&15, row = quad*4 + reg
    #pragma unroll
    for (int i = 0; i < 4; ++i) {
        const int rowbase = m0 + wm * 64 + i * 16 + quad * 4;
        float4 s4 = *(const float4*)(s_arr + rowbase);
        #pragma unroll
        for (int jj = 0; jj < 2; ++jj) {
            int gcol = n0 + wn * 32 + jj * 16 + l15;
            float bias = b1[gcol];
            #pragma unroll
            for (int r = 0; r < 4; ++r) {
                int grow = rowbase + r;
                float v = acc[i][jj][r] + bias;
                float sp = softplus_fast(v);
                float xv = bf2f(xb[grow * DM + gcol]);
                float sv = (r == 0) ? s4.x : (r == 1) ? s4.y : (r == 2) ? s4.z : s4.w;
                y[grow * DM + gcol] = xv * sp * sv;
            }
        }
    }
}

extern "C" void kernel_launch(void* const* d_in, const int* in_sizes, int n_in,
                              void* d_out, int out_size, void* d_ws, size_t ws_size,
                              hipStream_t stream) {
    const float* x  = (const float*)d_in[0];
    const float* W1 = (const float*)d_in[1];
    const float* b1 = (const float*)d_in[2];
    const float* W2 = (const float*)d_in[3];
    const float* b2 = (const float*)d_in[4];
    const float* W3 = (const float*)d_in[5];
    const float* b3 = (const float*)d_in[6];
    // d_in[7] = A : unused (multiplied by h0 == 0 in the reference)
    float* y = (float*)d_out;

    unsigned short* xb   = (unsigned short*)d_ws;                      // 12,582,912 B
    unsigned short* w1t  = (unsigned short*)((char*)d_ws + 12582912);  //  1,179,648 B
    unsigned short* w23t = (unsigned short*)((char*)d_ws + 13762560);  //     49,152 B
    float*          sarr = (float*)((char*)d_ws + 13811712);           //     32,768 B

    prep_kernel<<<6752, 256, 0, stream>>>(x, W1, W2, W3, xb, w1t, w23t);
    sgemm_kernel<<<128, 256, 0, stream>>>(xb, w23t, b2, b3, sarr);
    gemm_fused_kernel<<<768, 256, 0, stream>>>(xb, w1t, b1, sarr, y);
}

// Round 11
// 112.118 us; speedup vs baseline: 1.3564x; 1.3564x over previous
//
#include <hip/hip_runtime.h>
#include <hip/hip_bf16.h>
#include <math.h>

// Problem: B=4, L=2048 (M = 8192 rows), D_MODEL = 768, N_STATE = 16.
// y[row,d] = x[row,d] * softplus((x@W1+b1)[row,d]) * dot(x@W2+b2, x@W3+b3)[row]
// (dA*h0 term is identically zero; A unused.)
// Ledger: ~62 us harness fills (fixed). R10 lesson: register-pipelined
// direct-from-global GEMM loses 2x (compiler collapses the dbuf, vmcnt(0)
// serializes) -> LDS+barrier k-loop is the structure. R11: fold s into the
// gemm (s is row-local!), deleting the sgemm kernel + its straggler tail.

#define M_ROWS 8192
#define DM 768
#define NS 16

typedef short bf16x8 __attribute__((ext_vector_type(8)));
typedef float f32x4 __attribute__((ext_vector_type(4)));

__device__ __forceinline__ unsigned short f2bf(float f) {
    union { float f; unsigned u; } v; v.f = f;
    unsigned r = v.u + 0x7FFF + ((v.u >> 16) & 1);   // RNE
    return (unsigned short)(r >> 16);
}
__device__ __forceinline__ float bf2f(unsigned short h) {
    union { unsigned u; float f; } v; v.u = ((unsigned)h) << 16; return v.f;
}
__device__ __forceinline__ void async16(const void* g, void* l) {
    __builtin_amdgcn_global_load_lds(
        (const __attribute__((address_space(1))) void*)g,
        (__attribute__((address_space(3))) void*)l,
        16, 0, 0);
}
// branchless stable softplus: max(v,0) + log(1+exp(-|v|)); HW exp/log.
__device__ __forceinline__ float softplus_fast(float v) {
    return fmaxf(v, 0.f) + __logf(1.f + __expf(-fabsf(v)));
}

// ---- kernel 1: prep (pure streaming, block-specialized) -----------------
// bid [0,32):      w23t build (bf16 n-major, pair-interleaved W2/W3 cols).
// bid [32,608):    W1 [k][n] fp32 -> w1t [n][k] bf16 (32x32 LDS tiles).
// bid [608,6752):  streaming convert x -> xb (bf16), float4/thread.
__global__ __launch_bounds__(256) void prep_kernel(
    const float* __restrict__ x,
    const float* __restrict__ W1,
    const float* __restrict__ W2,
    const float* __restrict__ W3,
    unsigned short* __restrict__ xb,
    unsigned short* __restrict__ w1t,
    unsigned short* __restrict__ w23t)
{
    __shared__ float tile[32][33];
    const int bid = blockIdx.x;
    const int tid = threadIdx.x;
    if (bid < 32) {
        const int n = bid, i = n >> 1;
        const float* src = (n & 1) ? W3 : W2;
        #pragma unroll
        for (int e = 0; e < 3; ++e) {
            int k = e * 256 + tid;
            w23t[n * DM + k] = f2bf(src[k * NS + i]);
        }
    } else if (bid < 608) {
        const int b2i = bid - 32;                // 0..575
        const int n0 = (b2i % 24) * 32, k0 = (b2i / 24) * 32;
        const int tx = tid & 31, ty = tid >> 5;  // 32 x 8
        #pragma unroll
        for (int i = 0; i < 4; ++i) {
            int k = ty + i * 8;
            tile[k][tx] = W1[(k0 + k) * DM + n0 + tx];
        }
        __syncthreads();
        #pragma unroll
        for (int i = 0; i < 4; ++i) {
            int n = ty + i * 8;
            w1t[(n0 + n) * DM + k0 + tx] = f2bf(tile[tx][n]);
        }
    } else {
        int i = (bid - 608) * 256 + tid;         // one float4 per thread
        float4 v = ((const float4*)x)[i];
        ushort4 o;
        o.x = f2bf(v.x); o.y = f2bf(v.y); o.z = f2bf(v.z); o.w = f2bf(v.w);
        ((ushort4*)xb)[i] = o;
    }
}

// ---- kernel 2: fused GEMM + integrated s + softplus/scale epilogue ------
// R9-exact k-loop structure (single-buffered LDS, 2 barriers/step, 256 thr,
// 4 waves 2x2, 128x64 tile, BK=64, XCD swizzle) PLUS: stage w23t's 4 KB
// k-slice and compute P = xb_tile @ w23^T for this block's 128 rows.
// Wave (wm,wn) computes P-cols [wn*16, wn*16+16) for its 64 m-rows: 8 extra
// MFMAs/k-step reusing the A-fragments already in registers. Pair-product
// partials (8 pairs per wn) reduce via the verified R4 shfl algebra, then
// cross-wn combine through 1 KB LDS. s never leaves the block.
__global__ __launch_bounds__(256) void gemm_fused_kernel(
    const unsigned short* __restrict__ xb,    // [8192][768] bf16
    const unsigned short* __restrict__ w1t,   // [768][768] bf16, n-major
    const unsigned short* __restrict__ w23t,  // [32][768] bf16, pair-interleaved
    const float* __restrict__ b1,
    const float* __restrict__ b2, const float* __restrict__ b3,
    float* __restrict__ y)
{
    __shared__ unsigned short Al[128 * 64];   // 16 KB
    __shared__ unsigned short Bl[64 * 64];    //  8 KB
    __shared__ unsigned short Wl[32 * 64];    //  4 KB
    __shared__ float spart[2][128];           //  1 KB
    const int b = blockIdx.x;
    const int c = b & 7, j = b >> 3;          // j in [0,96)
    const int m0 = (c * 8 + j / 12) * 128;
    const int n0 = (j % 12) * 64;
    const int tid  = threadIdx.x;
    const int lane = tid & 63;
    const int wave = tid >> 6;
    const int wm = wave >> 1, wn = wave & 1;
    const int l15 = lane & 15, quad = lane >> 4;

    f32x4 acc[4][2];
    f32x4 accP[4];
    #pragma unroll
    for (int i = 0; i < 4; ++i) {
        accP[i] = (f32x4){0.f, 0.f, 0.f, 0.f};
        #pragma unroll
        for (int jj = 0; jj < 2; ++jj)
            acc[i][jj] = (f32x4){0.f, 0.f, 0.f, 0.f};
    }

    for (int k0 = 0; k0 < DM; k0 += 64) {
        #pragma unroll
        for (int i = 0; i < 4; ++i) {         // A: 1024 chunks
            int ch = tid + i * 256;
            int r = ch >> 3, jg = (ch & 7) ^ (r & 7);
            async16(xb + (m0 + r) * DM + k0 + jg * 8, Al + ch * 8);
        }
        #pragma unroll
        for (int i = 0; i < 2; ++i) {         // B: 512 chunks
            int ch = tid + i * 256;
            int r = ch >> 3, jg = (ch & 7) ^ (r & 7);
            async16(w1t + (n0 + r) * DM + k0 + jg * 8, Bl + ch * 8);
        }
        {                                      // W23: 256 chunks
            int ch = tid;
            int r = ch >> 3, jg = (ch & 7) ^ (r & 7);
            async16(w23t + r * DM + k0 + jg * 8, Wl + ch * 8);
        }
        __syncthreads();

        #pragma unroll
        for (int kk = 0; kk < 2; ++kk) {
            bf16x8 bfr[2], wfr;
            #pragma unroll
            for (int jj = 0; jj < 2; ++jj) {
                int rb = wn * 32 + jj * 16 + l15;
                int jb = (kk * 4 + quad) ^ (rb & 7);
                bfr[jj] = *(const bf16x8*)(Bl + rb * 64 + jb * 8);
            }
            {
                int rw = wn * 16 + l15;
                int jw = (kk * 4 + quad) ^ (rw & 7);
                wfr = *(const bf16x8*)(Wl + rw * 64 + jw * 8);
            }
            #pragma unroll
            for (int i = 0; i < 4; ++i) {
                int rr = wm * 64 + i * 16 + l15;
                int ja = (kk * 4 + quad) ^ (rr & 7);
                bf16x8 af = *(const bf16x8*)(Al + rr * 64 + ja * 8);
                #pragma unroll
                for (int jj = 0; jj < 2; ++jj)
                    acc[i][jj] = __builtin_amdgcn_mfma_f32_16x16x32_bf16(
                        af, bfr[jj], acc[i][jj], 0, 0, 0);
                accP[i] = __builtin_amdgcn_mfma_f32_16x16x32_bf16(
                    af, wfr, accP[i], 0, 0, 0);
            }
        }
        __syncthreads();
    }

    // ---- s partials: this wave owns pairs p = wn*8 + (l15>>1) ----
    {
        const int p = wn * 8 + (l15 >> 1);
        const float bB = b2[p], bC = b3[p];
        #pragma unroll
        for (int i = 0; i < 4; ++i) {
            float sacc[4];
            #pragma unroll
            for (int r = 0; r < 4; ++r) {
                float v = accP[i][r];
                float pv = __shfl_xor(v, 1, 64);
                sacc[r] = (l15 & 1) ? (pv + bB) * (v + bC)
                                    : (v + bB) * (pv + bC);
                sacc[r] += __shfl_xor(sacc[r], 1, 64);
                sacc[r] += __shfl_xor(sacc[r], 2, 64);
                sacc[r] += __shfl_xor(sacc[r], 4, 64);
                sacc[r] += __shfl_xor(sacc[r], 8, 64);
            }
            if (l15 == 0) {
                #pragma unroll
                for (int r = 0; r < 4; ++r)
                    spart[wn][wm * 64 + i * 16 + quad * 4 + r] = 0.5f * sacc[r];
            }
        }
    }
    __syncthreads();

    // ---- epilogue: C/D layout col = lane&15, row = quad*4 + reg ----
    #pragma unroll
    for (int i = 0; i < 4; ++i) {
        const int rl = wm * 64 + i * 16 + quad * 4;   // local row base
        const int rowbase = m0 + rl;
        float sv4[4];
        #pragma unroll
        for (int r = 0; r < 4; ++r)
            sv4[r] = spart[0][rl + r] + spart[1][rl + r];
        #pragma unroll
        for (int jj = 0; jj < 2; ++jj) {
            int gcol = n0 + wn * 32 + jj * 16 + l15;
            float bias = b1[gcol];
            #pragma unroll
            for (int r = 0; r < 4; ++r) {
                int grow = rowbase + r;
                float v = acc[i][jj][r] + bias;
                float sp = softplus_fast(v);
                float xv = bf2f(xb[grow * DM + gcol]);
                y[grow * DM + gcol] = xv * sp * sv4[r];
            }
        }
    }
}

extern "C" void kernel_launch(void* const* d_in, const int* in_sizes, int n_in,
                              void* d_out, int out_size, void* d_ws, size_t ws_size,
                              hipStream_t stream) {
    const float* x  = (const float*)d_in[0];
    const float* W1 = (const float*)d_in[1];
    const float* b1 = (const float*)d_in[2];
    const float* W2 = (const float*)d_in[3];
    const float* b2 = (const float*)d_in[4];
    const float* W3 = (const float*)d_in[5];
    const float* b3 = (const float*)d_in[6];
    // d_in[7] = A : unused (multiplied by h0 == 0 in the reference)
    float* y = (float*)d_out;

    unsigned short* xb   = (unsigned short*)d_ws;                      // 12,582,912 B
    unsigned short* w1t  = (unsigned short*)((char*)d_ws + 12582912);  //  1,179,648 B
    unsigned short* w23t = (unsigned short*)((char*)d_ws + 13762560);  //     49,152 B

    prep_kernel<<<6752, 256, 0, stream>>>(x, W1, W2, W3, xb, w1t, w23t);
    gemm_fused_kernel<<<768, 256, 0, stream>>>(xb, w1t, w23t, b1, b2, b3, y);
}